// Round 1
// baseline (176.998 us; speedup 1.0000x reference)
//
#include <hip/hip_runtime.h>
#include <cstdint>

// Hierarchical classification head: z_l = sigmoid(x @ Wl^T + bl) for 3 levels,
// logits via ancestor products, CE loss sum. Outputs: logits3 [4096,2800] fp32
// then loss scalar (out_size = 4096*2800+1).
//
// Structure: fp32->bf16 cast, one fused MFMA GEMM (N padded 3108->3200),
// per-row logits/loss kernel, final reduce.

typedef unsigned short u16;
typedef __bf16 bf16;
typedef bf16 bf16x8 __attribute__((ext_vector_type(8)));
typedef float f32x4 __attribute__((ext_vector_type(4)));

#define AS_G __attribute__((address_space(1)))
#define AS_L __attribute__((address_space(3)))

constexpr int BATCH = 4096;
constexpr int H     = 1024;
constexpr int N1 = 28, N2 = 280, N3 = 2800;
constexpr int NT = N1 + N2 + N3;   // 3108 real output columns
constexpr int NP = 3200;           // padded to 25 * 128

// ---------------- cast fp32 -> bf16 (RNE) + fused bias ----------------
__device__ inline u16 f2bf(float f) {
    unsigned int u = __float_as_uint(f);
    u += 0x7fffu + ((u >> 16) & 1u);
    return (u16)(u >> 16);
}

constexpr int XG = (BATCH * H) / 4;   // 1,048,576 float4 groups of x
constexpr int WG = (NP * H) / 4;      //   819,200 groups of W (padded)
constexpr int BG = NP / 4;            //       800 groups of bias

__global__ __launch_bounds__(256) void cast_kernel(
        const float* __restrict__ x,
        const float* __restrict__ W1, const float* __restrict__ W2,
        const float* __restrict__ W3,
        const float* __restrict__ b1, const float* __restrict__ b2,
        const float* __restrict__ b3,
        u16* __restrict__ Xb, u16* __restrict__ Wb, float* __restrict__ biasf) {
    int g = blockIdx.x * 256 + threadIdx.x;
    if (g < XG) {
        float4 v = ((const float4*)x)[g];
        ((ushort4*)Xb)[g] = make_ushort4(f2bf(v.x), f2bf(v.y), f2bf(v.z), f2bf(v.w));
    } else if (g < XG + WG) {
        int wg = g - XG;
        int row = wg >> 8;        // 256 groups per 1024-col row
        int cg  = wg & 255;
        float4 v = make_float4(0.f, 0.f, 0.f, 0.f);
        if (row < N1)           v = ((const float4*)W1)[row * 256 + cg];
        else if (row < N1 + N2) v = ((const float4*)W2)[(row - N1) * 256 + cg];
        else if (row < NT)      v = ((const float4*)W3)[(row - N1 - N2) * 256 + cg];
        ((ushort4*)Wb)[wg] = make_ushort4(f2bf(v.x), f2bf(v.y), f2bf(v.z), f2bf(v.w));
    } else if (g < XG + WG + BG) {
        int bg = g - XG - WG;
        float4 v;
        float* vp = &v.x;
        #pragma unroll
        for (int i = 0; i < 4; ++i) {
            int c = bg * 4 + i;
            float t = 0.f;
            if (c < N1)           t = b1[c];
            else if (c < N1 + N2) t = b2[c - N1];
            else if (c < NT)      t = b3[c - N1 - N2];
            vp[i] = t;
        }
        ((float4*)biasf)[bg] = v;
    }
}

// ---------------- GEMM: Z = sigmoid(Xb @ Wb^T + bias), fp32 out ----------------
// m97 structure: 128x128 tile, BK=32, 4 waves in 2x2, each wave 4x4 of 16x16x32.
__global__ __launch_bounds__(256) void gemm_sig(
        const u16* __restrict__ Xb, const u16* __restrict__ Wb,
        const float* __restrict__ biasf, float* __restrict__ Z) {
    __shared__ __align__(16) u16 As[128 * 32];
    __shared__ __align__(16) u16 Bs[128 * 32];
    const int tid  = threadIdx.x;
    const int lane = tid & 63;
    const int wave = tid >> 6;
    const int m0 = blockIdx.y * 128;
    const int n0 = blockIdx.x * 128;
    const int wr = wave >> 1;   // wave row (0..1) -> 64 rows
    const int wc = wave & 1;    // wave col (0..1) -> 64 cols

    // staging: 512 chunks of 16B per matrix tile; this thread does chunks tid, tid+256
    const int c0 = tid, c1 = tid + 256;
    const int r0 = c0 >> 2, o0 = (c0 & 3) * 8;
    const int r1 = c1 >> 2, o1 = (c1 & 3) * 8;

    const int laneM = lane & 15;
    const int laneK = (lane >> 4) * 8;

    f32x4 acc[4][4] = {};

    for (int kt = 0; kt < H / 32; ++kt) {
        const int k0 = kt * 32;
        __builtin_amdgcn_global_load_lds((const AS_G uint32_t*)(Xb + (size_t)(m0 + r0) * H + k0 + o0),
                                         (AS_L uint32_t*)&As[c0 * 8], 16, 0, 0);
        __builtin_amdgcn_global_load_lds((const AS_G uint32_t*)(Xb + (size_t)(m0 + r1) * H + k0 + o1),
                                         (AS_L uint32_t*)&As[c1 * 8], 16, 0, 0);
        __builtin_amdgcn_global_load_lds((const AS_G uint32_t*)(Wb + (size_t)(n0 + r0) * H + k0 + o0),
                                         (AS_L uint32_t*)&Bs[c0 * 8], 16, 0, 0);
        __builtin_amdgcn_global_load_lds((const AS_G uint32_t*)(Wb + (size_t)(n0 + r1) * H + k0 + o1),
                                         (AS_L uint32_t*)&Bs[c1 * 8], 16, 0, 0);
        __syncthreads();

        bf16x8 af[4], bfv[4];
        #pragma unroll
        for (int i = 0; i < 4; ++i) {
            af[i]  = *(const bf16x8*)&As[(wr * 64 + i * 16 + laneM) * 32 + laneK];
            bfv[i] = *(const bf16x8*)&Bs[(wc * 64 + i * 16 + laneM) * 32 + laneK];
        }
        #pragma unroll
        for (int am = 0; am < 4; ++am)
            #pragma unroll
            for (int bn = 0; bn < 4; ++bn)
                acc[am][bn] = __builtin_amdgcn_mfma_f32_16x16x32_bf16(af[am], bfv[bn], acc[am][bn], 0, 0, 0);
        __syncthreads();
    }

    // epilogue: C/D layout col = lane&15, row = (lane>>4)*4 + r
    #pragma unroll
    for (int bn = 0; bn < 4; ++bn) {
        const int col = n0 + wc * 64 + bn * 16 + laneM;
        if (col >= NT) continue;               // skip pad columns
        const float bias = biasf[col];
        #pragma unroll
        for (int am = 0; am < 4; ++am) {
            const int rbase = m0 + wr * 64 + am * 16 + (lane >> 4) * 4;
            #pragma unroll
            for (int r = 0; r < 4; ++r) {
                float v = acc[am][bn][r] + bias;
                Z[(size_t)(rbase + r) * NP + col] = 1.0f / (1.0f + __expf(-v));
            }
        }
    }
}

// ---------------- per-row logits + CE partials ----------------
__global__ __launch_bounds__(256) void logits_loss(
        const float* __restrict__ Z, const int* __restrict__ labels,
        float* __restrict__ out, float* __restrict__ partials) {
    __shared__ float z1s[N1];
    __shared__ float z2s[N2];
    __shared__ float z3s[N3];
    __shared__ float red[12];
    const int b = blockIdx.x, tid = threadIdx.x;
    const float* Zr = Z + (size_t)b * NP;
    for (int i = tid; i < NT; i += 256) {
        float v = Zr[i];
        if (i < N1)           z1s[i] = v;
        else if (i < N1 + N2) z2s[i - N1] = v;
        else                  z3s[i - N1 - N2] = v;
    }
    __syncthreads();

    float se1 = 0.f, se2 = 0.f, se3 = 0.f;
    float* outr = out + (size_t)b * N3;
    for (int k = tid; k < N3; k += 256) {
        float lg = z3s[k] * z3s[k / 10] * z3s[k / 100];
        outr[k] = lg;
        se3 += expf(lg);
    }
    for (int j = tid; j < N2; j += 256)
        se2 += expf(z2s[j] * z2s[j / 10]);
    if (tid < N1)
        se1 = expf(z1s[tid]);

    #pragma unroll
    for (int off = 32; off > 0; off >>= 1) {
        se1 += __shfl_down(se1, off, 64);
        se2 += __shfl_down(se2, off, 64);
        se3 += __shfl_down(se3, off, 64);
    }
    if ((tid & 63) == 0) {
        int w = tid >> 6;
        red[w] = se3; red[4 + w] = se2; red[8 + w] = se1;
    }
    __syncthreads();
    if (tid == 0) {
        float s3 = red[0] + red[1] + red[2] + red[3];
        float s2 = red[4] + red[5] + red[6] + red[7];
        float s1 = red[8] + red[9] + red[10] + red[11];
        int lab  = labels[b];
        int lab2 = lab / 10, lab1 = lab / 100;
        float l1 = z1s[lab1];
        float l2 = z2s[lab2] * z2s[lab2 / 10];
        float l3 = z3s[lab] * z3s[lab2] * z3s[lab1];
        partials[b] = (logf(s1) - l1) + (logf(s2) - l2) + (logf(s3) - l3);
    }
}

// ---------------- final loss reduce ----------------
__global__ __launch_bounds__(256) void final_reduce(
        const float* __restrict__ partials, float* __restrict__ out) {
    __shared__ float red[4];
    const int tid = threadIdx.x;
    float s = 0.f;
    for (int i = tid; i < BATCH; i += 256) s += partials[i];
    #pragma unroll
    for (int off = 32; off > 0; off >>= 1) s += __shfl_down(s, off, 64);
    if ((tid & 63) == 0) red[tid >> 6] = s;
    __syncthreads();
    if (tid == 0)
        out[(size_t)BATCH * N3] = (red[0] + red[1] + red[2] + red[3]) * (1.0f / BATCH);
}

extern "C" void kernel_launch(void* const* d_in, const int* in_sizes, int n_in,
                              void* d_out, int out_size, void* d_ws, size_t ws_size,
                              hipStream_t stream) {
    const float* x      = (const float*)d_in[0];
    const int*   labels = (const int*)d_in[1];
    const float* W1     = (const float*)d_in[2];
    const float* b1     = (const float*)d_in[3];
    const float* W2     = (const float*)d_in[4];
    const float* b2     = (const float*)d_in[5];
    const float* W3     = (const float*)d_in[6];
    const float* b3     = (const float*)d_in[7];
    float* out = (float*)d_out;

    char* ws = (char*)d_ws;
    u16*   Xb       = (u16*)ws;                       //  8,388,608 B  [4096][1024] bf16
    u16*   Wb       = (u16*)(ws + 8388608);           //  6,553,600 B  [3200][1024] bf16
    float* Z        = (float*)(ws + 14942208);        // 52,428,800 B  [4096][3200] fp32
    float* partials = (float*)(ws + 67371008);        //     16,384 B  [4096]
    float* biasf    = (float*)(ws + 67387392);        //     12,800 B  [3200]
    // total ws use: 67,400,192 B

    const int castGrid = (XG + WG + BG + 255) / 256;  // 7300
    cast_kernel<<<castGrid, 256, 0, stream>>>(x, W1, W2, W3, b1, b2, b3, Xb, Wb, biasf);
    gemm_sig<<<dim3(NP / 128, BATCH / 128), 256, 0, stream>>>(Xb, Wb, biasf, Z);
    logits_loss<<<BATCH, 256, 0, stream>>>(Z, labels, out, partials);
    final_reduce<<<1, 256, 0, stream>>>(partials, out);
}